// Round 15
// baseline (73.113 us; speedup 1.0000x reference)
//
#include <hip/hip_runtime.h>

// ---- problem constants (fixed by the reference) ----
#define BATCH   32
#define L1N     8192
#define L2N     32768
#define LTOT    40960
#define CD      32       // CONV_DEPTH
#define O1      256      // EMBED_DIM
#define L1P     1024     // L1N / 8
#define L2P     4096     // L2N / 8

typedef __attribute__((ext_vector_type(8))) _Float16 h16x8;
typedef __attribute__((ext_vector_type(4))) float f32x4;

// ---------------------------------------------------------------------------
// Fused pre-pass + scans.  grid.x = 320 blocks of 256:
//   blocks 0..31   : order1 scan;  blocks 32..63 : dst2 scan + cnt2
//   blocks 64..319 : weight conversion + combined vd tables + se tables
// w1s = fp16 conv1 weights stored in the EXACT swizzled LDS-image order.
// ---------------------------------------------------------------------------
__global__ __launch_bounds__(256) void k_prescan(
        const int* __restrict__ value,
        const float* __restrict__ w1, const float* __restrict__ w2,
        const float* __restrict__ ve1, const float* __restrict__ de1,
        const float* __restrict__ se1, const float* __restrict__ ve2,
        const float* __restrict__ de2, const float* __restrict__ se2,
        _Float16* __restrict__ w1s, _Float16* __restrict__ w2h,
        _Float16* __restrict__ vd1h, _Float16* __restrict__ vd2h,
        _Float16* __restrict__ se1h, _Float16* __restrict__ se2h,
        int* __restrict__ order1, int* __restrict__ dst2,
        int* __restrict__ cnt2) {
    int bid = blockIdx.x, tid = threadIdx.x;
    if (bid >= 64) {
        int i = (bid - 64) * 256 + tid;       // 65536 jobs
        if (i < 65536) {
            int kc = i >> 14, r = i & 16383, chunk = r >> 3, e = r & 7;
            int o = chunk >> 3, c16 = (chunk & 7) ^ (o & 7);
            int k = kc * 64 + c16 * 8 + e, s = k >> 5, c = k & 31;
            w1s[i] = (_Float16)w1[o * 256 + c * 8 + s];
        }
        if (i < 8192) {
            int o = i >> 8, k = i & 255, s = k >> 5, c = k & 31;
            w2h[i] = (_Float16)w2[o * 256 + c * 8 + s];
        }
        if (i < 3808) {                        // 119 rows x 32
            int row = i >> 5, c = i & 31;
            int v = row / 7, d = row % 7;
            vd1h[i] = (_Float16)(ve1[v * 32 + c] + de1[d * 32 + c]);
            vd2h[i] = (_Float16)(ve2[v * 32 + c] + de2[d * 32 + c]);
        }
        if (i < 12288) { se1h[i] = (_Float16)se1[i]; se2h[i] = (_Float16)se2[i]; }
        return;
    }
    int lane = tid & 63, wid = tid >> 6;
    __shared__ int wsum[4];
    if (bid < 32) {
        int b = bid;
        const int4* v = (const int4*)(value + b * LTOT) + tid * 8;  // 32 ints
        int4 r[8];
        #pragma unroll
        for (int j = 0; j < 8; ++j) r[j] = v[j];
        int cnt = 0;
        #pragma unroll
        for (int j = 0; j < 8; ++j)
            cnt += (r[j].x == 2) + (r[j].y == 2) + (r[j].z == 2) + (r[j].w == 2);
        int sc = cnt;
        #pragma unroll
        for (int d = 1; d < 64; d <<= 1) {
            int t = __shfl_up(sc, d);
            if (lane >= d) sc += t;
        }
        if (lane == 63) wsum[wid] = sc;
        __syncthreads();
        int base = 0;
        for (int w = 0; w < 4; ++w) if (w < wid) base += wsum[w];
        int run = base + sc - cnt;             // exclusive prefix
        int4* o = (int4*)(order1 + b * L1N + tid * 32);
        #pragma unroll
        for (int j = 0; j < 8; ++j) {
            int vv[4] = {r[j].x, r[j].y, r[j].z, r[j].w};
            int ot[4];
            #pragma unroll
            for (int i = 0; i < 4; ++i) {
                bool m = (vv[i] == 2);
                int ord = run < (L2P - 1) ? run : (L2P - 1);
                ot[i] = m ? ord : -1;
                run += m;
            }
            o[j] = make_int4(ot[0], ot[1], ot[2], ot[3]);
        }
    } else {
        int b = bid - 32;
        const int* v2 = value + b * LTOT + L1N + tid * 16 * 8;
        int m[16]; int cnt = 0;
        #pragma unroll
        for (int i = 0; i < 16; ++i) { m[i] = (v2[i * 8] != 0); cnt += m[i]; }
        int sc = cnt;
        #pragma unroll
        for (int d = 1; d < 64; d <<= 1) {
            int t = __shfl_up(sc, d);
            if (lane >= d) sc += t;
        }
        if (lane == 63) wsum[wid] = sc;
        __syncthreads();
        int base = 0;
        for (int w = 0; w < 4; ++w) if (w < wid) base += wsum[w];
        int run = base + sc - cnt;
        int* o = dst2 + b * L2P + tid * 16;
        #pragma unroll
        for (int i = 0; i < 16; i += 4) {
            int ot[4];
            #pragma unroll
            for (int k2 = 0; k2 < 4; ++k2) { ot[k2] = m[i + k2] ? run : -1; run += m[i + k2]; }
            *(int4*)(o + i) = make_int4(ot[0], ot[1], ot[2], ot[3]);
        }
        if (tid == 255) cnt2[b] = base + sc;
    }
}

// ---------------------------------------------------------------------------
// conv2 (MFMA f16, pipelined): embed2 -> GEMM M=131072,K=256,N=32 -> bias ->
// compact scatter (fp16, 16B stores via LDS repack).
// Block: 128 M-rows, 512 thr (8 waves x 16 rows).
// ---------------------------------------------------------------------------
__global__ __launch_bounds__(512, 2) void k_conv2(
    const int* __restrict__ value, const int* __restrict__ depth,
    const int* __restrict__ pos,
    const _Float16* __restrict__ vd2h, const _Float16* __restrict__ se2h,
    const _Float16* __restrict__ w2h, const float* __restrict__ b2,
    const int* __restrict__ dst2, _Float16* __restrict__ y_c) {
    int tid = threadIdx.x, lane = tid & 63, wid = tid >> 6;
    int q = tid & 3, tg = tid >> 2;           // 128 groups x 16B
    int g0 = blockIdx.x * 128, b = g0 >> 12, l2b = g0 & (L2P - 1);
    __shared__ _Float16 As[2][128 * 64];  // 16 KB x2
    __shared__ _Float16 Bs[32 * 256];     // 16 KB
    f32x4 acc[2] = {};
    int m0 = wid * 16;

    // ---- coalesced index staging into the As region (20 KB scratch) ----
    int* sval = (int*)&As[0][0];          // 1024 ints
    int* sdep = sval + 1024;              // 1024 ints
    int* spos = sdep + 1024;              // 3072 ints
    {
        int tok0 = b * LTOT + L1N + l2b * 8;
        if (tid < 256) ((int4*)sval)[tid] = ((const int4*)(value + tok0))[tid];
        else           ((int4*)sdep)[tid - 256] = ((const int4*)(depth + tok0))[tid - 256];
        const int4* psrc = (const int4*)(pos + (size_t)tok0 * 3);
        ((int4*)spos)[tid] = psrc[tid];                        // 0..511
        if (tid < 256) ((int4*)spos)[512 + tid] = psrc[512 + tid];  // 512..767
    }
    __syncthreads();
    int ivv[8], p0v[8], p1v[8], p2v[8];
    #pragma unroll
    for (int j = 0; j < 8; ++j) {
        int t = (j & 1) * 128 + tg;
        int tl = (t >> 1) * 8 + (j >> 1) * 2 + (t & 1);   // token in block
        ivv[j] = (sval[tl] * 7 + sdep[tl]) * CD;
        p0v[j] = spos[tl * 3] * CD;
        p1v[j] = (spos[tl * 3 + 1] + 128) * CD;
        p2v[j] = (spos[tl * 3 + 2] + 256) * CD;
    }
    __syncthreads();

    h16x8 row[2][4];
    #define PREF2(j, slot) { \
        row[slot][0] = *(const h16x8*)(vd2h + ivv[j] + q * 8); \
        row[slot][1] = *(const h16x8*)(se2h + p0v[j] + q * 8); \
        row[slot][2] = *(const h16x8*)(se2h + p1v[j] + q * 8); \
        row[slot][3] = *(const h16x8*)(se2h + p2v[j] + q * 8); }
    #define PACK2(j, slot, buf) { \
        int t = (j & 1) * 128 + tg, m = t >> 1, sh = t & 1; \
        h16x8 sum = (row[slot][0] + row[slot][1]) + \
                    (row[slot][2] + row[slot][3]); \
        int c16 = sh * 4 + q; \
        *(h16x8*)&As[buf][m * 64 + ((c16 ^ (m & 7)) * 8)] = sum; }

    PREF2(0, 0); PREF2(1, 1);
    // stage all of B once (1024 chunks, 2 iters)
    #pragma unroll
    for (int it = 0; it < 2; ++it) {
        int idx = it * 512 + tid;
        int o = idx >> 5, c16 = idx & 31;
        h16x8 v = *(const h16x8*)(w2h + o * 256 + c16 * 8);
        *(h16x8*)&Bs[o * 256 + ((c16 ^ (o & 7)) * 8)] = v;
    }
    PACK2(0, 0, 0); PACK2(1, 1, 0);
    __syncthreads();

    #pragma unroll
    for (int kc = 0; kc < 4; ++kc) {
        int cur = kc & 1;
        if (kc < 3) { PREF2(2 * kc + 2, 0); PREF2(2 * kc + 3, 1); }
        // ---- MFMA from As[cur] ----
        #pragma unroll
        for (int ks = 0; ks < 2; ++ks) {
            int c16a = ks * 4 + (lane >> 4);
            int r0 = m0 + (lane & 15);
            h16x8 a0 = *(const h16x8*)&As[cur][r0 * 64 + ((c16a ^ (r0 & 7)) * 8)];
            int c16b = kc * 8 + ks * 4 + (lane >> 4);
            #pragma unroll
            for (int nt = 0; nt < 2; ++nt) {
                int n = nt * 16 + (lane & 15);
                h16x8 bv = *(const h16x8*)&Bs[n * 256 + ((c16b ^ (n & 7)) * 8)];
                acc[nt] = __builtin_amdgcn_mfma_f32_16x16x32_f16(a0, bv, acc[nt], 0, 0, 0);
            }
        }
        if (kc < 3) { PACK2(2 * kc + 2, 0, cur ^ 1); PACK2(2 * kc + 3, 1, cur ^ 1); }
        __syncthreads();
    }

    // ---- epilogue: bias -> LDS repack (stride 40) -> 16B compact scatter ----
    _Float16* sm = &As[0][0];                 // 128 x 40 fp16 = 10 KB
    #pragma unroll
    for (int nt = 0; nt < 2; ++nt) {
        int n = nt * 16 + (lane & 15);
        float bias = b2[n];
        #pragma unroll
        for (int r = 0; r < 4; ++r) {
            int ml = m0 + (lane >> 4) * 4 + r;
            sm[ml * 40 + n] = (_Float16)(acc[nt][r] + bias);
        }
    }
    __syncthreads();
    {
        int rowi = tg;                        // 0..127
        int d = dst2[b * L2P + l2b + rowi];
        h16x8 v = *(const h16x8*)&sm[rowi * 40 + q * 8];
        if (d >= 0)
            *(h16x8*)(y_c + ((size_t)(b * L2P + d)) * CD + q * 8) = v;
    }
    #undef PREF2
    #undef PACK2
}

// ---------------------------------------------------------------------------
// conv1 (MFMA f16): embed1 + substitution gather -> GEMM M=32768,K=256,N=256.
// Block: 64M x 256N, 256 thr (4 waves 32Mx128N).
// As DOUBLE-buffered (16 KB) + Bs SINGLE (32 KB) = 48 KB -> 3 blocks/CU.
// Bs staged via global_load_lds from the pre-swizzled w1s image.
// ---------------------------------------------------------------------------
__global__ __launch_bounds__(256, 3) void k_conv1(
    const int* __restrict__ value, const int* __restrict__ depth,
    const int* __restrict__ pos,
    const _Float16* __restrict__ vd1h, const _Float16* __restrict__ se1h,
    const _Float16* __restrict__ w1s, const float* __restrict__ b1,
    const int* __restrict__ order1, const int* __restrict__ cnt2,
    const _Float16* __restrict__ y_c, float* __restrict__ out) {
    int tid = threadIdx.x, lane = tid & 63, wid = tid >> 6;
    int q = tid & 3, tg = tid >> 2;
    int g0 = blockIdx.x * 64, b = g0 >> 10, lb = g0 & (L1P - 1);
    __shared__ _Float16 smem[2 * 64 * 64 + 256 * 64];   // As x2 16KB | Bs 32KB
    _Float16* As0 = smem;
    _Float16* As1 = smem + 64 * 64;
    _Float16* Bs  = smem + 2 * 64 * 64;
    f32x4 acc[2][8] = {};
    int m0 = (wid & 1) * 32, n0 = (wid >> 1) * 128;
    int c2 = cnt2[b];

    // ---- coalesced index staging (12 KB overlay on As region) ----
    int* sval = (int*)smem;               // 512
    int* sord = sval + 512;               // 512
    int* sdep = sord + 512;               // 512
    int* spos = sdep + 512;               // 1536
    {
        int tok0 = b * LTOT + lb * 8;
        int o0 = b * L1N + lb * 8;
        const int4* vsrc = (const int4*)(value + tok0);
        const int4* dsrc = (const int4*)(depth + tok0);
        const int4* osrc = (const int4*)(order1 + o0);
        const int4* psrc = (const int4*)(pos + (size_t)tok0 * 3);
        if (tid < 128) { ((int4*)sval)[tid] = vsrc[tid]; ((int4*)sdep)[tid] = dsrc[tid]; }
        else { int o = tid - 128; ((int4*)sord)[o] = osrc[o]; ((int4*)spos)[o] = psrc[o]; }
        ((int4*)spos)[128 + tid] = psrc[128 + tid];    // 128..383
    }
    __syncthreads();
    int xv[8], p0v[8], p1v[8], p2v[8];
    #pragma unroll
    for (int j = 0; j < 8; ++j) {
        int t = (j & 1) * 64 + tg;
        int tl = (t >> 1) * 8 + (j >> 1) * 2 + (t & 1);
        int vv = sval[tl];
        if (vv == 2) {
            xv[j] = ~sord[tl];
            p0v[j] = 0; p1v[j] = 0; p2v[j] = 0;
        } else {
            xv[j] = (vv * 7 + sdep[tl]) * CD;
            p0v[j] = spos[tl * 3] * CD;
            p1v[j] = (spos[tl * 3 + 1] + 128) * CD;
            p2v[j] = (spos[tl * 3 + 2] + 256) * CD;
        }
    }
    __syncthreads();

    h16x8 row[2][4];
    #define PREF1(j, slot) { \
        int x_ = xv[j]; \
        h16x8 z = {}; \
        if (x_ < 0) { \
            int o_ = ~x_; \
            row[slot][0] = (o_ < c2) \
                ? *(const h16x8*)(y_c + ((size_t)(b * L2P + o_)) * CD + q * 8) : z; \
            row[slot][1] = z; row[slot][2] = z; row[slot][3] = z; \
        } else { \
            row[slot][0] = *(const h16x8*)(vd1h + x_ + q * 8); \
            row[slot][1] = *(const h16x8*)(se1h + p0v[j] + q * 8); \
            row[slot][2] = *(const h16x8*)(se1h + p1v[j] + q * 8); \
            row[slot][3] = *(const h16x8*)(se1h + p2v[j] + q * 8); \
        } }
    #define PACK1(j, slot, ABUF) { \
        int t_ = (j & 1) * 64 + tg, m_ = t_ >> 1, sh_ = t_ & 1; \
        h16x8 sum = (row[slot][0] + row[slot][1]) + \
                    (row[slot][2] + row[slot][3]); \
        int c16 = sh_ * 4 + q; \
        *(h16x8*)&ABUF[m_ * 64 + ((c16 ^ (m_ & 7)) * 8)] = sum; }
    // Bs staging: 2048 chunks of 16 B, linear in LDS (w1s is pre-swizzled).
    #define BSTAGE(kc) { \
        _Pragma("unroll") \
        for (int it = 0; it < 8; ++it) { \
            int chunk = it * 256 + tid; \
            __builtin_amdgcn_global_load_lds( \
                (const __attribute__((address_space(1))) void*)(w1s + (kc) * 16384 + chunk * 8), \
                (__attribute__((address_space(3))) void*)(Bs + (it * 256 + (wid << 6)) * 8), \
                16, 0, 0); } }

    BSTAGE(0);
    PREF1(0, 0); PREF1(1, 1);
    PACK1(0, 0, As0); PACK1(1, 1, As0);
    __syncthreads();                          // vmcnt(0): Bs + As0 ready

    #pragma unroll
    for (int kc = 0; kc < 4; ++kc) {
        _Float16* Acur = (kc & 1) ? As1 : As0;
        _Float16* Anxt = (kc & 1) ? As0 : As1;
        if (kc < 3) { PREF1(2 * kc + 2, 0); PREF1(2 * kc + 3, 1); }
        // ---- MFMA: 2 m-frags x 8 n-frags x 2 K-steps ----
        #pragma unroll
        for (int ks = 0; ks < 2; ++ks) {
            int c16 = ks * 4 + (lane >> 4);
            int r0 = m0 + (lane & 15), r1 = r0 + 16;
            h16x8 a0 = *(const h16x8*)&Acur[r0 * 64 + ((c16 ^ (r0 & 7)) * 8)];
            h16x8 a1 = *(const h16x8*)&Acur[r1 * 64 + ((c16 ^ (r1 & 7)) * 8)];
            #pragma unroll
            for (int nt = 0; nt < 8; ++nt) {
                int n = n0 + nt * 16 + (lane & 15);
                h16x8 bv = *(const h16x8*)&Bs[n * 64 + ((c16 ^ (n & 7)) * 8)];
                acc[0][nt] = __builtin_amdgcn_mfma_f32_16x16x32_f16(a0, bv, acc[0][nt], 0, 0, 0);
                acc[1][nt] = __builtin_amdgcn_mfma_f32_16x16x32_f16(a1, bv, acc[1][nt], 0, 0, 0);
            }
        }
        __syncthreads();                      // all waves done reading Bs/Acur
        if (kc < 3) {
            BSTAGE(kc + 1);
            PACK1(2 * kc + 2, 0, Anxt); PACK1(2 * kc + 3, 1, Anxt);
            __syncthreads();                  // vmcnt(0): new Bs + As visible
        }
    }

    // ---- epilogue: bias + fp32 store ----
    #pragma unroll
    for (int nt = 0; nt < 8; ++nt) {
        int n = n0 + nt * 16 + (lane & 15);
        float bias = b1[n];
        #pragma unroll
        for (int mt = 0; mt < 2; ++mt)
            #pragma unroll
            for (int r = 0; r < 4; ++r) {
                int g = g0 + m0 + mt * 16 + (lane >> 4) * 4 + r;
                out[(size_t)g * O1 + n] = acc[mt][nt][r] + bias;
            }
    }
    #undef PREF1
    #undef PACK1
    #undef BSTAGE
}

// ---------------------------------------------------------------------------
extern "C" void kernel_launch(void* const* d_in, const int* in_sizes, int n_in,
                              void* d_out, int out_size, void* d_ws, size_t ws_size,
                              hipStream_t stream) {
    const int* value = (const int*)d_in[0];
    const int* depth = (const int*)d_in[1];
    const int* pos   = (const int*)d_in[2];
    const float* ve1 = (const float*)d_in[5];
    const float* de1 = (const float*)d_in[6];
    const float* se1 = (const float*)d_in[7];
    const float* ve2 = (const float*)d_in[8];
    const float* de2 = (const float*)d_in[9];
    const float* se2 = (const float*)d_in[10];
    const float* w1  = (const float*)d_in[11];
    const float* b1  = (const float*)d_in[12];
    const float* w2  = (const float*)d_in[13];
    const float* b2  = (const float*)d_in[14];
    float* out = (float*)d_out;

    char* ws = (char*)d_ws;
    _Float16* w1s  = (_Float16*)(ws);                         // 128 KB
    _Float16* w2h  = (_Float16*)(ws + 131072);                // 16 KB
    _Float16* vd1h = (_Float16*)(ws + 147456);                // 8 KB slot
    _Float16* vd2h = (_Float16*)(ws + 155648);                // 8 KB slot
    _Float16* se1h = (_Float16*)(ws + 163840);                // 24 KB
    _Float16* se2h = (_Float16*)(ws + 188416);                // 24 KB
    _Float16* y_c  = (_Float16*)(ws + 212992);                // 8 MB
    int* order1 = (int*)(ws + 212992 + 8388608);              // 1 MB
    int* dst2   = (int*)(ws + 212992 + 8388608 + 1048576);    // 512 KB
    int* cnt2   = (int*)(ws + 212992 + 8388608 + 1048576 + 524288); // 128 B

    k_prescan<<<320, 256, 0, stream>>>(value, w1, w2, ve1, de1, se1,
                                       ve2, de2, se2, w1s, w2h,
                                       vd1h, vd2h, se1h, se2h,
                                       order1, dst2, cnt2);
    // conv2 launched 3x (idempotent) -- measurement probe:
    // dur_us ~= 43.6 + 2*t_conv2(warm).
    k_conv2<<<1024, 512, 0, stream>>>(value, depth, pos, vd2h, se2h,
                                      w2h, b2, dst2, y_c);
    k_conv2<<<1024, 512, 0, stream>>>(value, depth, pos, vd2h, se2h,
                                      w2h, b2, dst2, y_c);
    k_conv2<<<1024, 512, 0, stream>>>(value, depth, pos, vd2h, se2h,
                                      w2h, b2, dst2, y_c);
    k_conv1<<<512, 256, 0, stream>>>(value, depth, pos, vd1h, se1h,
                                     w1s, b1, order1, cnt2, y_c, out);
}

// Round 16
// 43.240 us; speedup vs baseline: 1.6909x; 1.6909x over previous
//
#include <hip/hip_runtime.h>

// ---- problem constants (fixed by the reference) ----
#define BATCH   32
#define L1N     8192
#define L2N     32768
#define LTOT    40960
#define CD      32       // CONV_DEPTH
#define O1      256      // EMBED_DIM
#define L1P     1024     // L1N / 8
#define L2P     4096     // L2N / 8

typedef __attribute__((ext_vector_type(8))) _Float16 h16x8;
typedef __attribute__((ext_vector_type(4))) float f32x4;

// ---------------------------------------------------------------------------
// Kernel 1: scans + conv2-side table prep.  grid = 112 blocks of 256:
//   blocks 0..31  : order1 scan;  blocks 32..63 : dst2 scan + cnt2
//   blocks 64..111: w2h / vd2h / se2h conversion (parallel, independent)
// ---------------------------------------------------------------------------
__global__ __launch_bounds__(256) void k_scan(
        const int* __restrict__ value,
        const float* __restrict__ w2,
        const float* __restrict__ ve2, const float* __restrict__ de2,
        const float* __restrict__ se2,
        _Float16* __restrict__ w2h, _Float16* __restrict__ vd2h,
        _Float16* __restrict__ se2h,
        int* __restrict__ order1, int* __restrict__ dst2,
        int* __restrict__ cnt2) {
    int bid = blockIdx.x, tid = threadIdx.x;
    if (bid >= 64) {
        int i = (bid - 64) * 256 + tid;       // 12288 jobs
        if (i < 8192) {
            int o = i >> 8, k = i & 255, s = k >> 5, c = k & 31;
            w2h[i] = (_Float16)w2[o * 256 + c * 8 + s];
        }
        if (i < 3808) {                        // 119 rows x 32
            int row = i >> 5, c = i & 31;
            int v = row / 7, d = row % 7;
            vd2h[i] = (_Float16)(ve2[v * 32 + c] + de2[d * 32 + c]);
        }
        if (i < 12288) se2h[i] = (_Float16)se2[i];
        return;
    }
    int lane = tid & 63, wid = tid >> 6;
    __shared__ int wsum[4];
    if (bid < 32) {
        int b = bid;
        const int4* v = (const int4*)(value + b * LTOT) + tid * 8;  // 32 ints
        int4 r[8];
        #pragma unroll
        for (int j = 0; j < 8; ++j) r[j] = v[j];
        int cnt = 0;
        #pragma unroll
        for (int j = 0; j < 8; ++j)
            cnt += (r[j].x == 2) + (r[j].y == 2) + (r[j].z == 2) + (r[j].w == 2);
        int sc = cnt;
        #pragma unroll
        for (int d = 1; d < 64; d <<= 1) {
            int t = __shfl_up(sc, d);
            if (lane >= d) sc += t;
        }
        if (lane == 63) wsum[wid] = sc;
        __syncthreads();
        int base = 0;
        for (int w = 0; w < 4; ++w) if (w < wid) base += wsum[w];
        int run = base + sc - cnt;             // exclusive prefix
        int4* o = (int4*)(order1 + b * L1N + tid * 32);
        #pragma unroll
        for (int j = 0; j < 8; ++j) {
            int vv[4] = {r[j].x, r[j].y, r[j].z, r[j].w};
            int ot[4];
            #pragma unroll
            for (int i = 0; i < 4; ++i) {
                bool m = (vv[i] == 2);
                int ord = run < (L2P - 1) ? run : (L2P - 1);
                ot[i] = m ? ord : -1;
                run += m;
            }
            o[j] = make_int4(ot[0], ot[1], ot[2], ot[3]);
        }
    } else {
        int b = bid - 32;
        const int* v2 = value + b * LTOT + L1N + tid * 16 * 8;
        int m[16]; int cnt = 0;
        #pragma unroll
        for (int i = 0; i < 16; ++i) { m[i] = (v2[i * 8] != 0); cnt += m[i]; }
        int sc = cnt;
        #pragma unroll
        for (int d = 1; d < 64; d <<= 1) {
            int t = __shfl_up(sc, d);
            if (lane >= d) sc += t;
        }
        if (lane == 63) wsum[wid] = sc;
        __syncthreads();
        int base = 0;
        for (int w = 0; w < 4; ++w) if (w < wid) base += wsum[w];
        int run = base + sc - cnt;
        int* o = dst2 + b * L2P + tid * 16;
        #pragma unroll
        for (int i = 0; i < 16; i += 4) {
            int ot[4];
            #pragma unroll
            for (int k2 = 0; k2 < 4; ++k2) { ot[k2] = m[i + k2] ? run : -1; run += m[i + k2]; }
            *(int4*)(o + i) = make_int4(ot[0], ot[1], ot[2], ot[3]);
        }
        if (tid == 255) cnt2[b] = base + sc;
    }
}

// ---------------------------------------------------------------------------
// Kernel 2: conv2 (blocks 0..1023) + conv1-side table prep (blocks 1024..1151).
// conv2: MFMA f16, pipelined, 128 M-rows, 512 thr (8 waves x 16 rows).
// prep: w1s (swizzled LDS image) / vd1h / se1h — independent of conv2,
// hides under it; kernel boundary publishes to conv1.
// ---------------------------------------------------------------------------
__global__ __launch_bounds__(512, 2) void k_conv2(
    const int* __restrict__ value, const int* __restrict__ depth,
    const int* __restrict__ pos,
    const _Float16* __restrict__ vd2h, const _Float16* __restrict__ se2h,
    const _Float16* __restrict__ w2h, const float* __restrict__ b2,
    const int* __restrict__ dst2, _Float16* __restrict__ y_c,
    const float* __restrict__ w1, const float* __restrict__ ve1,
    const float* __restrict__ de1, const float* __restrict__ se1,
    _Float16* __restrict__ w1s, _Float16* __restrict__ vd1h,
    _Float16* __restrict__ se1h) {
    int tid = threadIdx.x, lane = tid & 63, wid = tid >> 6;
    if (blockIdx.x >= 1024) {
        int i = (blockIdx.x - 1024) * 512 + tid;   // 65536 jobs
        if (i < 65536) {
            int kc = i >> 14, r = i & 16383, chunk = r >> 3, e = r & 7;
            int o = chunk >> 3, c16 = (chunk & 7) ^ (o & 7);
            int k = kc * 64 + c16 * 8 + e, s = k >> 5, c = k & 31;
            w1s[i] = (_Float16)w1[o * 256 + c * 8 + s];
        }
        if (i < 3808) {
            int row = i >> 5, c = i & 31;
            int v = row / 7, d = row % 7;
            vd1h[i] = (_Float16)(ve1[v * 32 + c] + de1[d * 32 + c]);
        }
        if (i < 12288) se1h[i] = (_Float16)se1[i];
        return;
    }
    int q = tid & 3, tg = tid >> 2;           // 128 groups x 16B
    int g0 = blockIdx.x * 128, b = g0 >> 12, l2b = g0 & (L2P - 1);
    __shared__ _Float16 As[2][128 * 64];  // 16 KB x2
    __shared__ _Float16 Bs[32 * 256];     // 16 KB
    f32x4 acc[2] = {};
    int m0 = wid * 16;

    // ---- coalesced index staging into the As region (20 KB scratch) ----
    int* sval = (int*)&As[0][0];          // 1024 ints
    int* sdep = sval + 1024;              // 1024 ints
    int* spos = sdep + 1024;              // 3072 ints
    {
        int tok0 = b * LTOT + L1N + l2b * 8;
        if (tid < 256) ((int4*)sval)[tid] = ((const int4*)(value + tok0))[tid];
        else           ((int4*)sdep)[tid - 256] = ((const int4*)(depth + tok0))[tid - 256];
        const int4* psrc = (const int4*)(pos + (size_t)tok0 * 3);
        ((int4*)spos)[tid] = psrc[tid];                        // 0..511
        if (tid < 256) ((int4*)spos)[512 + tid] = psrc[512 + tid];  // 512..767
    }
    __syncthreads();
    int ivv[8], p0v[8], p1v[8], p2v[8];
    #pragma unroll
    for (int j = 0; j < 8; ++j) {
        int t = (j & 1) * 128 + tg;
        int tl = (t >> 1) * 8 + (j >> 1) * 2 + (t & 1);   // token in block
        ivv[j] = (sval[tl] * 7 + sdep[tl]) * CD;
        p0v[j] = spos[tl * 3] * CD;
        p1v[j] = (spos[tl * 3 + 1] + 128) * CD;
        p2v[j] = (spos[tl * 3 + 2] + 256) * CD;
    }
    __syncthreads();

    h16x8 row[2][4];
    #define PREF2(j, slot) { \
        row[slot][0] = *(const h16x8*)(vd2h + ivv[j] + q * 8); \
        row[slot][1] = *(const h16x8*)(se2h + p0v[j] + q * 8); \
        row[slot][2] = *(const h16x8*)(se2h + p1v[j] + q * 8); \
        row[slot][3] = *(const h16x8*)(se2h + p2v[j] + q * 8); }
    #define PACK2(j, slot, buf) { \
        int t = (j & 1) * 128 + tg, m = t >> 1, sh = t & 1; \
        h16x8 sum = (row[slot][0] + row[slot][1]) + \
                    (row[slot][2] + row[slot][3]); \
        int c16 = sh * 4 + q; \
        *(h16x8*)&As[buf][m * 64 + ((c16 ^ (m & 7)) * 8)] = sum; }

    PREF2(0, 0); PREF2(1, 1);
    // stage all of B once (1024 chunks, 2 iters)
    #pragma unroll
    for (int it = 0; it < 2; ++it) {
        int idx = it * 512 + tid;
        int o = idx >> 5, c16 = idx & 31;
        h16x8 v = *(const h16x8*)(w2h + o * 256 + c16 * 8);
        *(h16x8*)&Bs[o * 256 + ((c16 ^ (o & 7)) * 8)] = v;
    }
    PACK2(0, 0, 0); PACK2(1, 1, 0);
    __syncthreads();

    #pragma unroll
    for (int kc = 0; kc < 4; ++kc) {
        int cur = kc & 1;
        if (kc < 3) { PREF2(2 * kc + 2, 0); PREF2(2 * kc + 3, 1); }
        // ---- MFMA from As[cur] ----
        #pragma unroll
        for (int ks = 0; ks < 2; ++ks) {
            int c16a = ks * 4 + (lane >> 4);
            int r0 = m0 + (lane & 15);
            h16x8 a0 = *(const h16x8*)&As[cur][r0 * 64 + ((c16a ^ (r0 & 7)) * 8)];
            int c16b = kc * 8 + ks * 4 + (lane >> 4);
            #pragma unroll
            for (int nt = 0; nt < 2; ++nt) {
                int n = nt * 16 + (lane & 15);
                h16x8 bv = *(const h16x8*)&Bs[n * 256 + ((c16b ^ (n & 7)) * 8)];
                acc[nt] = __builtin_amdgcn_mfma_f32_16x16x32_f16(a0, bv, acc[nt], 0, 0, 0);
            }
        }
        if (kc < 3) { PACK2(2 * kc + 2, 0, cur ^ 1); PACK2(2 * kc + 3, 1, cur ^ 1); }
        __syncthreads();
    }

    // ---- epilogue: bias -> LDS repack (stride 40) -> 16B compact scatter ----
    _Float16* sm = &As[0][0];                 // 128 x 40 fp16 = 10 KB
    #pragma unroll
    for (int nt = 0; nt < 2; ++nt) {
        int n = nt * 16 + (lane & 15);
        float bias = b2[n];
        #pragma unroll
        for (int r = 0; r < 4; ++r) {
            int ml = m0 + (lane >> 4) * 4 + r;
            sm[ml * 40 + n] = (_Float16)(acc[nt][r] + bias);
        }
    }
    __syncthreads();
    {
        int rowi = tg;                        // 0..127
        int d = dst2[b * L2P + l2b + rowi];
        h16x8 v = *(const h16x8*)&sm[rowi * 40 + q * 8];
        if (d >= 0)
            *(h16x8*)(y_c + ((size_t)(b * L2P + d)) * CD + q * 8) = v;
    }
    #undef PREF2
    #undef PACK2
}

// ---------------------------------------------------------------------------
// conv1 (MFMA f16): embed1 + substitution gather -> GEMM M=32768,K=256,N=256.
// Block: 64M x 256N, 256 thr (4 waves 32Mx128N).
// As DOUBLE-buffered (16 KB) + Bs SINGLE (32 KB) = 48 KB -> 3 blocks/CU.
// Bs staged via global_load_lds from the pre-swizzled w1s image.
// ---------------------------------------------------------------------------
__global__ __launch_bounds__(256, 3) void k_conv1(
    const int* __restrict__ value, const int* __restrict__ depth,
    const int* __restrict__ pos,
    const _Float16* __restrict__ vd1h, const _Float16* __restrict__ se1h,
    const _Float16* __restrict__ w1s, const float* __restrict__ b1,
    const int* __restrict__ order1, const int* __restrict__ cnt2,
    const _Float16* __restrict__ y_c, float* __restrict__ out) {
    int tid = threadIdx.x, lane = tid & 63, wid = tid >> 6;
    int q = tid & 3, tg = tid >> 2;
    int g0 = blockIdx.x * 64, b = g0 >> 10, lb = g0 & (L1P - 1);
    __shared__ _Float16 smem[2 * 64 * 64 + 256 * 64];   // As x2 16KB | Bs 32KB
    _Float16* As0 = smem;
    _Float16* As1 = smem + 64 * 64;
    _Float16* Bs  = smem + 2 * 64 * 64;
    f32x4 acc[2][8] = {};
    int m0 = (wid & 1) * 32, n0 = (wid >> 1) * 128;
    int c2 = cnt2[b];

    // ---- coalesced index staging (12 KB overlay on As region) ----
    int* sval = (int*)smem;               // 512
    int* sord = sval + 512;               // 512
    int* sdep = sord + 512;               // 512
    int* spos = sdep + 512;               // 1536
    {
        int tok0 = b * LTOT + lb * 8;
        int o0 = b * L1N + lb * 8;
        const int4* vsrc = (const int4*)(value + tok0);
        const int4* dsrc = (const int4*)(depth + tok0);
        const int4* osrc = (const int4*)(order1 + o0);
        const int4* psrc = (const int4*)(pos + (size_t)tok0 * 3);
        if (tid < 128) { ((int4*)sval)[tid] = vsrc[tid]; ((int4*)sdep)[tid] = dsrc[tid]; }
        else { int o = tid - 128; ((int4*)sord)[o] = osrc[o]; ((int4*)spos)[o] = psrc[o]; }
        ((int4*)spos)[128 + tid] = psrc[128 + tid];    // 128..383
    }
    __syncthreads();
    int xv[8], p0v[8], p1v[8], p2v[8];
    #pragma unroll
    for (int j = 0; j < 8; ++j) {
        int t = (j & 1) * 64 + tg;
        int tl = (t >> 1) * 8 + (j >> 1) * 2 + (t & 1);
        int vv = sval[tl];
        if (vv == 2) {
            xv[j] = ~sord[tl];
            p0v[j] = 0; p1v[j] = 0; p2v[j] = 0;
        } else {
            xv[j] = (vv * 7 + sdep[tl]) * CD;
            p0v[j] = spos[tl * 3] * CD;
            p1v[j] = (spos[tl * 3 + 1] + 128) * CD;
            p2v[j] = (spos[tl * 3 + 2] + 256) * CD;
        }
    }
    __syncthreads();

    h16x8 row[2][4];
    #define PREF1(j, slot) { \
        int x_ = xv[j]; \
        h16x8 z = {}; \
        if (x_ < 0) { \
            int o_ = ~x_; \
            row[slot][0] = (o_ < c2) \
                ? *(const h16x8*)(y_c + ((size_t)(b * L2P + o_)) * CD + q * 8) : z; \
            row[slot][1] = z; row[slot][2] = z; row[slot][3] = z; \
        } else { \
            row[slot][0] = *(const h16x8*)(vd1h + x_ + q * 8); \
            row[slot][1] = *(const h16x8*)(se1h + p0v[j] + q * 8); \
            row[slot][2] = *(const h16x8*)(se1h + p1v[j] + q * 8); \
            row[slot][3] = *(const h16x8*)(se1h + p2v[j] + q * 8); \
        } }
    #define PACK1(j, slot, ABUF) { \
        int t_ = (j & 1) * 64 + tg, m_ = t_ >> 1, sh_ = t_ & 1; \
        h16x8 sum = (row[slot][0] + row[slot][1]) + \
                    (row[slot][2] + row[slot][3]); \
        int c16 = sh_ * 4 + q; \
        *(h16x8*)&ABUF[m_ * 64 + ((c16 ^ (m_ & 7)) * 8)] = sum; }
    // Bs staging: 2048 chunks of 16 B, linear in LDS (w1s is pre-swizzled).
    #define BSTAGE(kc) { \
        _Pragma("unroll") \
        for (int it = 0; it < 8; ++it) { \
            int chunk = it * 256 + tid; \
            __builtin_amdgcn_global_load_lds( \
                (const __attribute__((address_space(1))) void*)(w1s + (kc) * 16384 + chunk * 8), \
                (__attribute__((address_space(3))) void*)(Bs + (it * 256 + (wid << 6)) * 8), \
                16, 0, 0); } }

    BSTAGE(0);
    PREF1(0, 0); PREF1(1, 1);
    PACK1(0, 0, As0); PACK1(1, 1, As0);
    __syncthreads();                          // vmcnt(0): Bs + As0 ready

    #pragma unroll
    for (int kc = 0; kc < 4; ++kc) {
        _Float16* Acur = (kc & 1) ? As1 : As0;
        _Float16* Anxt = (kc & 1) ? As0 : As1;
        if (kc < 3) { PREF1(2 * kc + 2, 0); PREF1(2 * kc + 3, 1); }
        // ---- MFMA: 2 m-frags x 8 n-frags x 2 K-steps ----
        #pragma unroll
        for (int ks = 0; ks < 2; ++ks) {
            int c16 = ks * 4 + (lane >> 4);
            int r0 = m0 + (lane & 15), r1 = r0 + 16;
            h16x8 a0 = *(const h16x8*)&Acur[r0 * 64 + ((c16 ^ (r0 & 7)) * 8)];
            h16x8 a1 = *(const h16x8*)&Acur[r1 * 64 + ((c16 ^ (r1 & 7)) * 8)];
            #pragma unroll
            for (int nt = 0; nt < 8; ++nt) {
                int n = n0 + nt * 16 + (lane & 15);
                h16x8 bv = *(const h16x8*)&Bs[n * 64 + ((c16 ^ (n & 7)) * 8)];
                acc[0][nt] = __builtin_amdgcn_mfma_f32_16x16x32_f16(a0, bv, acc[0][nt], 0, 0, 0);
                acc[1][nt] = __builtin_amdgcn_mfma_f32_16x16x32_f16(a1, bv, acc[1][nt], 0, 0, 0);
            }
        }
        __syncthreads();                      // all waves done reading Bs/Acur
        if (kc < 3) {
            BSTAGE(kc + 1);
            PACK1(2 * kc + 2, 0, Anxt); PACK1(2 * kc + 3, 1, Anxt);
            __syncthreads();                  // vmcnt(0): new Bs + As visible
        }
    }

    // ---- epilogue: bias + fp32 store ----
    #pragma unroll
    for (int nt = 0; nt < 8; ++nt) {
        int n = n0 + nt * 16 + (lane & 15);
        float bias = b1[n];
        #pragma unroll
        for (int mt = 0; mt < 2; ++mt)
            #pragma unroll
            for (int r = 0; r < 4; ++r) {
                int g = g0 + m0 + mt * 16 + (lane >> 4) * 4 + r;
                out[(size_t)g * O1 + n] = acc[mt][nt][r] + bias;
            }
    }
    #undef PREF1
    #undef PACK1
    #undef BSTAGE
}

// ---------------------------------------------------------------------------
extern "C" void kernel_launch(void* const* d_in, const int* in_sizes, int n_in,
                              void* d_out, int out_size, void* d_ws, size_t ws_size,
                              hipStream_t stream) {
    const int* value = (const int*)d_in[0];
    const int* depth = (const int*)d_in[1];
    const int* pos   = (const int*)d_in[2];
    const float* ve1 = (const float*)d_in[5];
    const float* de1 = (const float*)d_in[6];
    const float* se1 = (const float*)d_in[7];
    const float* ve2 = (const float*)d_in[8];
    const float* de2 = (const float*)d_in[9];
    const float* se2 = (const float*)d_in[10];
    const float* w1  = (const float*)d_in[11];
    const float* b1  = (const float*)d_in[12];
    const float* w2  = (const float*)d_in[13];
    const float* b2  = (const float*)d_in[14];
    float* out = (float*)d_out;

    char* ws = (char*)d_ws;
    _Float16* w1s  = (_Float16*)(ws);                         // 128 KB
    _Float16* w2h  = (_Float16*)(ws + 131072);                // 16 KB
    _Float16* vd1h = (_Float16*)(ws + 147456);                // 8 KB slot
    _Float16* vd2h = (_Float16*)(ws + 155648);                // 8 KB slot
    _Float16* se1h = (_Float16*)(ws + 163840);                // 24 KB
    _Float16* se2h = (_Float16*)(ws + 188416);                // 24 KB
    _Float16* y_c  = (_Float16*)(ws + 212992);                // 8 MB
    int* order1 = (int*)(ws + 212992 + 8388608);              // 1 MB
    int* dst2   = (int*)(ws + 212992 + 8388608 + 1048576);    // 512 KB
    int* cnt2   = (int*)(ws + 212992 + 8388608 + 1048576 + 524288); // 128 B

    k_scan<<<112, 256, 0, stream>>>(value, w2, ve2, de2, se2,
                                    w2h, vd2h, se2h, order1, dst2, cnt2);
    k_conv2<<<1152, 512, 0, stream>>>(value, depth, pos, vd2h, se2h,
                                      w2h, b2, dst2, y_c,
                                      w1, ve1, de1, se1, w1s, vd1h, se1h);
    k_conv1<<<512, 256, 0, stream>>>(value, depth, pos, vd1h, se1h,
                                     w1s, b1, order1, cnt2, y_c, out);
}